// Round 10
// baseline (6028.340 us; speedup 1.0000x reference)
//
#include <hip/hip_runtime.h>
#include <hip/hip_bf16.h>

#define B   128
#define NA  8
#define AD  16
#define DM  512
#define DI  1024
#define DS  32
#define DC  4
#define DR  32
#define NB  4
#define OD  128

typedef __hip_bfloat16 bf16;
typedef unsigned int uint32;
typedef unsigned short ushort16;

__device__ __forceinline__ float bf2f(bf16 h){ return __bfloat162float(h); }
__device__ __forceinline__ float sigmoidf_(float x){ return 1.0f/(1.0f+__expf(-x)); }
__device__ __forceinline__ float softplusf_(float x){ return fmaxf(x,0.0f)+log1pf(__expf(-fabsf(x))); }
__device__ __forceinline__ float lo2f(uint32 u){ return __uint_as_float(u<<16); }
__device__ __forceinline__ float hi2f(uint32 u){ return __uint_as_float(u & 0xffff0000u); }
__device__ __forceinline__ uint32 packbf2(float a, float b){
    bf16 ha = __float2bfloat16(a), hb = __float2bfloat16(b);
    ushort16 sa = *reinterpret_cast<ushort16*>(&ha);
    ushort16 sb = *reinterpret_cast<ushort16*>(&hb);
    return (uint32)sa | ((uint32)sb << 16);
}
__device__ __forceinline__ ushort16 f2us(float a){
    bf16 ha = __float2bfloat16(a);
    return *reinterpret_cast<ushort16*>(&ha);
}

// ---------------- setup kernels ----------------

__global__ __launch_bounds__(256) void k_negA(const float* __restrict__ Als,
    const float* __restrict__ Alc, float* __restrict__ negA)
{
    int idx = blockIdx.x*256 + threadIdx.x;   // < 2*NB*DI*DS
    int bs = idx >> 15;
    int r  = idx & 32767;
    int nb = bs >> 1, st = bs & 1;
    const float* src = (st ? Alc : Als) + (size_t)nb*DI*DS + r;
    negA[idx] = -__expf(*src);
}

__global__ __launch_bounds__(256) void k_ctx(const float* __restrict__ obs_rep,
    const float* __restrict__ obs, const float* __restrict__ Wobs,
    float* __restrict__ ctx)
{
    int ib = blockIdx.x;          // < B*8
    int b = ib >> 3, i = ib & 7;
    __shared__ float orow[OD];
    int tid = threadIdx.x;
    if (tid < OD) orow[tid] = obs[(size_t)(b*NA+i)*OD + tid];
    __syncthreads();
    for (int m = tid; m < DM; m += 256){
        float acc = obs_rep[(size_t)(b*NA+i)*DM + m];
        for (int o = 0; o < OD; o++)
            acc += orow[o]*Wobs[o*DM + m];
        ctx[(size_t)(i*B + b)*DM + m] = acc;
    }
}

// W1b[bs][k][c] bf16, straight cast of in_proj [512][2048]
__global__ __launch_bounds__(256) void k_w1(const float* __restrict__ Ws,
    const float* __restrict__ Wc, ushort16* __restrict__ W1b)
{
    int idx = blockIdx.x*256 + threadIdx.x;   // < 8*1048576
    int bs = idx >> 20;
    int r  = idx & 1048575;
    int nb = bs >> 1, st = bs & 1;
    const float* src = (st ? Wc : Ws) + (size_t)nb*1048576 + r;
    W1b[idx] = f2us(*src);
}

// Wob[bs][k][c] bf16, straight cast of out_proj [1024][512]
__global__ __launch_bounds__(256) void k_wo(const float* __restrict__ Ws,
    const float* __restrict__ Wc, ushort16* __restrict__ Wob)
{
    int idx = blockIdx.x*256 + threadIdx.x;   // < 8*524288
    int bs = idx >> 19;
    int r  = idx & 524287;
    int nb = bs >> 1, st = bs & 1;
    const float* src = (st ? Wc : Ws) + (size_t)nb*DI*DM + r;
    Wob[idx] = f2us(*src);
}

// Wxb[bs][j][k] bf16 — transposed x_proj: [8][96][1024]
__global__ __launch_bounds__(256) void k_wx(const float* __restrict__ Ws,
    const float* __restrict__ Wc, ushort16* __restrict__ Wxb)
{
    int idx = blockIdx.x*256 + threadIdx.x;   // < 8*98304
    int bs = idx / 98304;
    int r  = idx % 98304;
    int j  = r >> 10, k = r & 1023;
    int nb = bs >> 1, st = bs & 1;
    const float* src = (st ? Wc : Ws) + (size_t)nb*DI*96 + (size_t)k*96 + j;
    Wxb[idx] = f2us(*src);
}

// Wdtb[bs][r][d] bf16 [8][32][1024]
__global__ __launch_bounds__(256) void k_wdt(const float* __restrict__ Ws,
    const float* __restrict__ Wc, ushort16* __restrict__ Wdtb)
{
    int idx = blockIdx.x*256 + threadIdx.x;   // < 8*32768
    int bs = idx >> 15;
    int r  = idx & 32767;
    int nb = bs >> 1, st = bs & 1;
    const float* src = (st ? Wc : Ws) + (size_t)nb*DR*DI + r;
    Wdtb[idx] = f2us(*src);
}

__global__ __launch_bounds__(256) void k_init(const float* __restrict__ bemb,
    float* __restrict__ xb0)
{
    int idx = blockIdx.x*256 + threadIdx.x;   // < B*DM
    xb0[idx] = bemb[idx & (DM-1)];
}

// ---------------- per-step kernels ----------------

// g1: LN(x)[+ctx] staged transposed in LDS; xz = uln @ W_in (VALU, row-tiled);
// conv ring + silu epilogue. grid 256 = 8 row-tiles(16) x 32 col-tiles(64). 512 thr.
__global__ __launch_bounds__(512) void k_g1(
    const float* __restrict__ xin, const float* __restrict__ lns,
    const float* __restrict__ ctxG, const bf16* __restrict__ W1b,
    bf16* __restrict__ ring, const float* __restrict__ cw,
    const float* __restrict__ cb, float* __restrict__ xcG,
    float* __restrict__ szG, int i, int st, int bs)
{
    int bx = blockIdx.x & 31;   // col-tile
    int by = blockIdx.x >> 5;   // row-tile
    int t = threadIdx.x;
    __shared__ float ulnT[512][18];    // [k][row], padded stride
    __shared__ float red[1024];
    __shared__ float mrow[16], rrow[16];

    // stats: 32 threads/row x 16 elems
    {
        int row = t >> 5, part = t & 31;
        const float* xp = xin + (size_t)(by*16 + row)*DM + part*16;
        float s = 0.f, q = 0.f;
        #pragma unroll
        for (int e = 0; e < 16; e++){ float v = xp[e]; s += v; q += v*v; }
        red[t] = s; red[512 + t] = q;
    }
    __syncthreads();
    if (t < 16){
        float s = 0.f, q = 0.f;
        for (int p = 0; p < 32; p++){ s += red[t*32+p]; q += red[512+t*32+p]; }
        float m = s*(1.0f/512.0f);
        float v = q*(1.0f/512.0f) - m*m;
        mrow[t] = m; rrow[t] = rsqrtf(v + 1e-5f);
    }
    __syncthreads();
    // normalize + transpose into LDS
    for (int idx = t; idx < 8192; idx += 512){
        int row = idx >> 9, k = idx & 511;
        float u = (xin[(size_t)(by*16+row)*DM + k] - mrow[row])*rrow[row]*lns[k];
        if (st) u += ctxG[((size_t)i*B + by*16 + row)*DM + k];
        ulnT[k][row] = u;
    }
    __syncthreads();

    int colg = bx*64 + (t & 63);
    int rg = t >> 6;              // 0..7 -> rows rg*2, rg*2+1 (wave-uniform)
    const bf16* wp = W1b + ((size_t)bs << 20) + colg;
    float acc0 = 0.f, acc1 = 0.f;
    #pragma unroll 8
    for (int k = 0; k < 512; k++){
        float2 a = *(const float2*)&ulnT[k][rg*2];
        float w = bf2f(wp[(size_t)k*2048]);
        acc0 += a.x*w; acc1 += a.y*w;
    }

    float vv[2] = {acc0, acc1};
    if (colg < DI){
        int d = colg;
        float c0 = cw[0*DI+d], c1 = cw[1*DI+d], c2 = cw[2*DI+d], c3 = cw[3*DI+d];
        float cbd = cb[d];
        #pragma unroll
        for (int r = 0; r < 2; r++){
            int rowg = by*16 + rg*2 + r;
            float v = vv[r];
            ring[(((size_t)bs*4 + (i&3))*B + rowg)*DI + d] = __float2bfloat16(v);
            float sum = cbd + c3*v;
            if (i >= 1) sum += c2*bf2f(ring[(((size_t)bs*4 + ((i-1)&3))*B + rowg)*DI + d]);
            if (i >= 2) sum += c1*bf2f(ring[(((size_t)bs*4 + ((i-2)&3))*B + rowg)*DI + d]);
            if (i >= 3) sum += c0*bf2f(ring[(((size_t)bs*4 + ((i-3)&3))*B + rowg)*DI + d]);
            xcG[(size_t)rowg*DI + d] = sum*sigmoidf_(sum);
        }
    } else {
        int d = colg - DI;
        #pragma unroll
        for (int r = 0; r < 2; r++){
            int rowg = by*16 + rg*2 + r;
            szG[(size_t)rowg*DI + d] = vv[r]*sigmoidf_(vv[r]);
        }
    }
}

// state: xproj GEMV + dt + h update + yz. grid 256 (row x d-half), 512 thr.
// (R8's verified step2, minus the gemm2 tail.)
__global__ __launch_bounds__(512) void k_state(
    const float* __restrict__ xcG, const float* __restrict__ szG,
    const bf16* __restrict__ Wxb, const bf16* __restrict__ Wdtb,
    const float* __restrict__ dtb, const float* __restrict__ Dp,
    const float* __restrict__ negA, uint32* __restrict__ hG,
    float* __restrict__ yzG, int first, int bs)
{
    int row = blockIdx.x >> 1, hx = blockIdx.x & 1;
    int t = threadIdx.x;
    __shared__ float xcL[1024];
    __shared__ float partx[384];
    __shared__ float rowS[96];

    xcL[t]       = xcG[(size_t)row*DI + t];
    xcL[512 + t] = xcG[(size_t)row*DI + 512 + t];
    __syncthreads();

    if (t < 384){
        int sl = t / 96, j = t - sl*96;
        int k0 = sl*256;
        const uint4* wx4 = (const uint4*)((const ushort16*)Wxb + (size_t)bs*98304 + (size_t)j*1024 + k0);
        float acc = 0.f;
        #pragma unroll 4
        for (int ii = 0; ii < 32; ii++){
            uint4 q4 = wx4[ii];
            int kk = k0 + 8*ii;
            acc += xcL[kk+0]*lo2f(q4.x) + xcL[kk+1]*hi2f(q4.x)
                 + xcL[kk+2]*lo2f(q4.y) + xcL[kk+3]*hi2f(q4.y)
                 + xcL[kk+4]*lo2f(q4.z) + xcL[kk+5]*hi2f(q4.z)
                 + xcL[kk+6]*lo2f(q4.w) + xcL[kk+7]*hi2f(q4.w);
        }
        partx[t] = acc;
    }
    __syncthreads();
    if (t < 96) rowS[t] = partx[t] + partx[t+96] + partx[t+192] + partx[t+288];
    __syncthreads();

    {
        int d = hx*512 + t;
        float dp = dtb[d];
        const bf16* wdt = Wdtb + ((size_t)bs << 15);
        #pragma unroll 8
        for (int r = 0; r < DR; r++)
            dp += rowS[r]*bf2f(wdt[(size_t)r*DI + d]);
        float delta = softplusf_(dp);
        float xcv = xcL[d];
        float dxc = delta*xcv;
        const float4* nap = (const float4*)(negA + ((size_t)bs << 15) + (size_t)d*DS);
        uint4* hp = (uint4*)(hG + (((size_t)bs*B + row)*DI + d)*16);
        float y = 0.f;
        #pragma unroll
        for (int qq = 0; qq < 4; qq++){
            uint4 hu = first ? make_uint4(0u,0u,0u,0u) : hp[qq];
            float4 na0 = nap[2*qq], na1 = nap[2*qq+1];
            int s0 = 8*qq;
            float h0 = lo2f(hu.x), h1 = hi2f(hu.x);
            float h2 = lo2f(hu.y), h3 = hi2f(hu.y);
            float h4 = lo2f(hu.z), h5 = hi2f(hu.z);
            float h6 = lo2f(hu.w), h7 = hi2f(hu.w);
            h0 = __expf(delta*na0.x)*h0 + dxc*rowS[DR+s0+0];
            h1 = __expf(delta*na0.y)*h1 + dxc*rowS[DR+s0+1];
            h2 = __expf(delta*na0.z)*h2 + dxc*rowS[DR+s0+2];
            h3 = __expf(delta*na0.w)*h3 + dxc*rowS[DR+s0+3];
            h4 = __expf(delta*na1.x)*h4 + dxc*rowS[DR+s0+4];
            h5 = __expf(delta*na1.y)*h5 + dxc*rowS[DR+s0+5];
            h6 = __expf(delta*na1.z)*h6 + dxc*rowS[DR+s0+6];
            h7 = __expf(delta*na1.w)*h7 + dxc*rowS[DR+s0+7];
            y += h0*rowS[DR+DS+s0+0] + h1*rowS[DR+DS+s0+1]
               + h2*rowS[DR+DS+s0+2] + h3*rowS[DR+DS+s0+3]
               + h4*rowS[DR+DS+s0+4] + h5*rowS[DR+DS+s0+5]
               + h6*rowS[DR+DS+s0+6] + h7*rowS[DR+DS+s0+7];
            hu.x = packbf2(h0,h1); hu.y = packbf2(h2,h3);
            hu.z = packbf2(h4,h5); hu.w = packbf2(h6,h7);
            hp[qq] = hu;
        }
        y += Dp[d]*xcv;
        yzG[(size_t)row*DI + d] = y*szG[(size_t)row*DI + d];
    }
}

// g2: x_next = x_prev + yz @ W_out (VALU, row-tiled).
// grid 256 = 16 row-tiles(8) x 16 col-tiles(32). 256 thr.
__global__ __launch_bounds__(256) void k_g2(
    const float* __restrict__ yzG, const bf16* __restrict__ Wob,
    const float* __restrict__ xin, float* __restrict__ xout, int bs)
{
    int bx = blockIdx.x & 15;   // col-tile (32 cols)
    int by = blockIdx.x >> 4;   // row-tile (8 rows)
    int t = threadIdx.x;
    __shared__ float yzT[1024][10];   // [k][row], padded
    for (int idx = t; idx < 8192; idx += 256){
        int row = idx >> 10, k = idx & 1023;
        yzT[k][row] = yzG[(size_t)(by*8 + row)*DI + k];
    }
    __syncthreads();
    int col = bx*32 + (t & 31);
    int rg = t >> 5;   // 0..7 = row within tile
    const bf16* wp = Wob + (size_t)bs*DI*DM + col;
    float acc = 0.f;
    #pragma unroll 8
    for (int k = 0; k < 1024; k++)
        acc += yzT[k][rg]*bf2f(wp[(size_t)k*DM]);
    int rowg = by*8 + rg;
    xout[(size_t)rowg*DM + col] = xin[(size_t)rowg*DM + col] + acc;
}

// head: LN, W_head GEMV, outputs; next x = act@Wemb + bemb. grid B, 512 thr.
__global__ __launch_bounds__(512) void k_head(
    const float* __restrict__ xin, float* __restrict__ xout,
    const float* __restrict__ lno, const float* __restrict__ Whead,
    const float* __restrict__ logstd, const float* __restrict__ eps,
    const float* __restrict__ Wemb, const float* __restrict__ bemb,
    float* __restrict__ out, int agent)
{
    int b = blockIdx.x, t = threadIdx.x, lane = t & 63, wid = t >> 6;
    __shared__ float ulnL[512];
    __shared__ float redH[512];
    __shared__ float wps[8], wpq[8], ms2[2];
    __shared__ float actv[AD], lpterm[AD];

    float v = xin[(size_t)b*DM + t];
    float s = v, q = v*v;
    for (int off = 32; off > 0; off >>= 1){
        s += __shfl_down(s, off);
        q += __shfl_down(q, off);
    }
    if (lane == 0){ wps[wid] = s; wpq[wid] = q; }
    __syncthreads();
    if (t == 0){
        float S = 0.f, Q = 0.f;
        #pragma unroll
        for (int w2 = 0; w2 < 8; w2++){ S += wps[w2]; Q += wpq[w2]; }
        float m = S*(1.0f/DM);
        float var = Q*(1.0f/DM) - m*m;
        ms2[0] = m; ms2[1] = rsqrtf(var + 1e-5f);
    }
    __syncthreads();
    ulnL[t] = (v - ms2[0])*ms2[1]*lno[t];
    __syncthreads();
    {
        int ks = t >> 4, j = t & 15;
        float acc = 0.f;
        int k0 = ks*16;
        #pragma unroll
        for (int k = k0; k < k0 + 16; k++)
            acc += ulnL[k]*Whead[k*AD + j];
        redH[t] = acc;
    }
    __syncthreads();
    if (t < AD){
        int j = t;
        float mean = 0.f;
        #pragma unroll
        for (int ks = 0; ks < 32; ks++) mean += redH[ks*16 + j];
        float stdj = softplusf_(logstd[j]);
        float e = eps[((size_t)b*NA + agent)*AD + j];
        float raw = mean + stdj*e;
        float act = tanhf(raw);
        out[((size_t)b*NA + agent)*AD + j] = act;                                    // acts
        out[(size_t)NA*B*AD + (size_t)B*NA + ((size_t)b*NA + agent)*AD + j] = raw;   // raws
        actv[j] = act;
        lpterm[j] = -0.5f*e*e - logf(stdj)
                    - 2.0f*(0.69314718f - raw - softplusf_(-2.0f*raw));
    }
    __syncthreads();
    if (t == 0){
        float lp = 0.f;
        #pragma unroll
        for (int j = 0; j < AD; j++) lp += lpterm[j];
        lp -= 0.5f*AD*1.8378770664f;
        out[(size_t)NA*B*AD + (size_t)b*NA + agent] = lp;                            // logs
    }
    float v2 = bemb[t];
    #pragma unroll
    for (int j = 0; j < AD; j++)
        v2 += actv[j]*Wemb[j*DM + t];
    xout[(size_t)b*DM + t] = v2;
}

// ---------------- launch ----------------

extern "C" void kernel_launch(void* const* d_in, const int* in_sizes, int n_in,
                              void* d_out, int out_size, void* d_ws, size_t ws_size,
                              hipStream_t stream)
{
    const float* in[29];
    for (int k = 0; k < 29; k++) in[k] = (const float*)d_in[k];

    // workspace layout (bytes), total ~103 MB (known-safe)
    char* wsb = (char*)d_ws;
    bf16*   W1b  = (bf16*)  (wsb + 0);           // [8][512][2048] bf16 = 16 MB
    bf16*   Wob  = (bf16*)  (wsb + 16777216);    // [8][1024][512] bf16 =  8 MB
    bf16*   Wxb  = (bf16*)  (wsb + 25165824);    // [8][96][1024]        1.5 MB
    bf16*   Wdtb = (bf16*)  (wsb + 26738688);    // [8][32][1024]        0.5 MB
    float*  negA = (float*) (wsb + 27262976);    // [8][1024][32] f32      1 MB
    float*  ctx  = (float*) (wsb + 28311552);    // [8][128][512] f32      2 MB
    float*  xb0  = (float*) (wsb + 30408704);    // [128][512] f32
    float*  xb1  = (float*) (wsb + 30670848);
    float*  xcG  = (float*) (wsb + 30932992);    // [128][1024] f32
    float*  szG  = (float*) (wsb + 31457280);
    float*  yzG  = (float*) (wsb + 31981568);
    bf16*   ring = (bf16*)  (wsb + 32505856);    // [8][4][128][1024] bf16 = 8 MB
    uint32* hG   = (uint32*)(wsb + 40894464);    // 64 MB

    float* out = (float*)d_out;
    float* xb[2] = {xb0, xb1};

    k_negA<<<dim3(1024),  256, 0, stream>>>(in[17], in[26], negA);
    k_ctx <<<dim3(B*NA),  256, 0, stream>>>(in[0], in[1], in[5], ctx);
    k_w1  <<<dim3(32768), 256, 0, stream>>>(in[11], in[20], (ushort16*)W1b);
    k_wo  <<<dim3(16384), 256, 0, stream>>>(in[19], in[28], (ushort16*)Wob);
    k_wx  <<<dim3(3072),  256, 0, stream>>>(in[14], in[23], (ushort16*)Wxb);
    k_wdt <<<dim3(1024),  256, 0, stream>>>(in[15], in[24], (ushort16*)Wdtb);
    k_init<<<dim3(256),   256, 0, stream>>>(in[4], xb0);

    int cur = 0;
    for (int i = 0; i < NA; i++){
        for (int nb = 0; nb < NB; nb++){
            for (int st = 0; st < 2; st++){
                int bs = nb*2 + st;
                int base = st ? 20 : 11;
                const float* cw   = in[base+1] + (size_t)nb*DC*DI;
                const float* cb   = in[base+2] + (size_t)nb*DI;
                const float* dtbp = in[base+5] + (size_t)nb*DI;
                const float* Dpp  = in[base+7] + (size_t)nb*DI;
                const float* lns  = (st ? in[7] : in[6]) + (size_t)nb*DM;

                k_g1<<<dim3(256), 512, 0, stream>>>(xb[cur], lns, ctx, W1b,
                        ring, cw, cb, xcG, szG, i, st, bs);
                k_state<<<dim3(256), 512, 0, stream>>>(xcG, szG, Wxb, Wdtb,
                        dtbp, Dpp, negA, hG, yzG, (i==0) ? 1 : 0, bs);
                k_g2<<<dim3(256), 256, 0, stream>>>(yzG, Wob, xb[cur], xb[cur^1], bs);
                cur ^= 1;
            }
        }
        k_head<<<dim3(B), 512, 0, stream>>>(xb[cur], xb[cur^1],
                in[8], in[9], in[10], in[2], in[3], in[4], out, i);
        cur ^= 1;
    }
}